// Round 20
// baseline (90.636 us; speedup 1.0000x reference)
//
#include <hip/hip_runtime.h>

// TopKGate via split-precision f16 MFMA (no fp32 MFMA on CDNA4):
//   x = xh + xl/4096, w = wh + wl/4096 (f16 planes, lo pre-scaled x4096)
//   logits = xh*wh + (xh*wl' + xl'*wh)/4096
// R20: K SPLIT ACROSS BLOCKS -> grid 2048 = 1024 token-tiles x 2 K-halves,
// 8 blocks/CU (2x TLP). Each block: 8 chunks of BK=128, NBUF=2, one barrier
// per chunk, w direct-to-fragment (batched 2 tiles to keep VGPR <= 64).
// Blocks write f32 logit-partials; finish kernel sums halves + softmax/top2.

typedef __attribute__((ext_vector_type(8))) _Float16 half8;
typedef __attribute__((ext_vector_type(4))) float f32x4;

constexpr int DD  = 2048;
constexpr int EE  = 64;
constexpr int BM  = 16;          // tokens per tile
constexpr int BK  = 128;         // k per staged chunk
constexpr int NCH = 8;           // chunks per half (K=1024)

#define WVM(N) asm volatile("s_waitcnt vmcnt(" #N ")" ::: "memory")
#define BAR()  asm volatile("s_barrier" ::: "memory")

// ---- pre-kernel (R15-proven): Wg[2048][64] -> fragment-linear wF ----
// wF[(kc*8 + t*2 + p)*512 + l*8 + j] = plane_p( Wg[kc*32+(l>>4)*8+j][t*16+(l&15)] )
__global__ __launch_bounds__(256) void wsplit_kernel(
    const float* __restrict__ Wg, _Float16* __restrict__ wF)
{
    __shared__ float xl[32][65];
    const int tid = threadIdx.x;
    const int kc  = blockIdx.x;          // 64 blocks, 32 k's each
    const int k0  = kc * 32;
#pragma unroll
    for (int r = 0; r < 2; ++r) {
        int slot = tid + r * 256;        // float4 slots 0..511
        int row = slot >> 4, c4 = (slot & 15) << 2;
        *(float4*)&xl[row][c4] = *(const float4*)&Wg[(size_t)(k0 + row) * EE + c4];
    }
    __syncthreads();
    const int t = tid >> 6, l = tid & 63;
    const int e  = t * 16 + (l & 15);
    const int kl = (l >> 4) * 8;
    half8 hh, ll;
#pragma unroll
    for (int j = 0; j < 8; ++j) {
        float v = xl[kl + j][e];
        _Float16 h = (_Float16)v;
        hh[j] = h;
        ll[j] = (_Float16)((v - (float)h) * 4096.f);
    }
    const size_t base = (size_t)(kc * 8 + t * 2) * 512 + (size_t)l * 8;
    *(half8*)&wF[base]       = hh;       // hi plane
    *(half8*)&wF[base + 512] = ll;       // lo plane
}

__global__ __launch_bounds__(256, 4) void gate_kernel(
    const float* __restrict__ x, const _Float16* __restrict__ wF,
    float* __restrict__ partial)
{
    __shared__ __align__(16) union {
        float xs[2][BM][BK];             // 16 KB staging (2 bufs)
        float red[4][BM][65];            // 16.6 KB kq-reduction
    } sm;

    const int tid  = threadIdx.x;
    const int kq   = tid >> 6;           // wave = K-quarter of chunk (32 k's)
    const int lane = tid & 63;
    const int tile = blockIdx.x >> 1;    // token tile 0..1023
    const int kb   = blockIdx.x & 1;     // K-half 0..1
    const size_t tok0 = (size_t)tile * BM;
    const float* xg = x + tok0 * DD + kb * 1024;

    // ---- x staging: 2 dwordx4 DMA per thread per chunk, 32B source-XOR ----
    auto stageX = [&](int buf, int c) {
#pragma unroll
        for (int r = 0; r < 2; ++r) {
            int slot = tid + r * 256;            // float4 slot 0..511
            int row  = slot >> 5;                // 0..15
            int cb   = (slot & 31) << 4;         // dest byte 0..511 (linear)
            int sb   = cb ^ ((row & 7) << 5);    // source-swizzled byte
            __builtin_amdgcn_global_load_lds(
                xg + (size_t)row * DD + c * BK + (sb >> 2),
                &sm.xs[buf][row][cb >> 2], 16, 0, 0);
        }
    };

    f32x4 aH[4], aL[4];
#pragma unroll
    for (int t = 0; t < 4; ++t) {
        aH[t] = (f32x4){0.f, 0.f, 0.f, 0.f};
        aL[t] = (f32x4){0.f, 0.f, 0.f, 0.f};
    }

    const int rrow = lane & 15;          // token row
    const int rb   = (kq * 128 + ((lane >> 4) * 32)) ^ ((rrow & 7) << 5);

    auto compute = [&](int buf, int c) {
        // this wave's 32-k slice: global slice index kb*32 + c*4 + kq
        const _Float16* wb = wF + (size_t)(kb * 32 + c * 4 + kq) * 4096
                                + (size_t)lane * 8;
        // x fragment: one 8-float read, split once
        const float* p = (const float*)((const char*)&sm.xs[buf][rrow][0] + rb);
        float4 xa = *(const float4*)p;
        float4 xb = *(const float4*)(p + 4);
        half8 ah, al;
        {
            float v;
            v = xa.x; { _Float16 h=(_Float16)v; ah[0]=h; al[0]=(_Float16)((v-(float)h)*4096.f); }
            v = xa.y; { _Float16 h=(_Float16)v; ah[1]=h; al[1]=(_Float16)((v-(float)h)*4096.f); }
            v = xa.z; { _Float16 h=(_Float16)v; ah[2]=h; al[2]=(_Float16)((v-(float)h)*4096.f); }
            v = xa.w; { _Float16 h=(_Float16)v; ah[3]=h; al[3]=(_Float16)((v-(float)h)*4096.f); }
            v = xb.x; { _Float16 h=(_Float16)v; ah[4]=h; al[4]=(_Float16)((v-(float)h)*4096.f); }
            v = xb.y; { _Float16 h=(_Float16)v; ah[5]=h; al[5]=(_Float16)((v-(float)h)*4096.f); }
            v = xb.z; { _Float16 h=(_Float16)v; ah[6]=h; al[6]=(_Float16)((v-(float)h)*4096.f); }
            v = xb.w; { _Float16 h=(_Float16)v; ah[7]=h; al[7]=(_Float16)((v-(float)h)*4096.f); }
        }
        // tiles 0,1 (batched to keep live w-regs at 16)
        {
            half8 wh0 = *(const half8*)(wb + 0 * 512);
            half8 wl0 = *(const half8*)(wb + 1 * 512);
            half8 wh1 = *(const half8*)(wb + 2 * 512);
            half8 wl1 = *(const half8*)(wb + 3 * 512);
            aH[0] = __builtin_amdgcn_mfma_f32_16x16x32_f16(ah, wh0, aH[0], 0, 0, 0);
            aL[0] = __builtin_amdgcn_mfma_f32_16x16x32_f16(ah, wl0, aL[0], 0, 0, 0);
            aL[0] = __builtin_amdgcn_mfma_f32_16x16x32_f16(al, wh0, aL[0], 0, 0, 0);
            aH[1] = __builtin_amdgcn_mfma_f32_16x16x32_f16(ah, wh1, aH[1], 0, 0, 0);
            aL[1] = __builtin_amdgcn_mfma_f32_16x16x32_f16(ah, wl1, aL[1], 0, 0, 0);
            aL[1] = __builtin_amdgcn_mfma_f32_16x16x32_f16(al, wh1, aL[1], 0, 0, 0);
        }
        // tiles 2,3
        {
            half8 wh2 = *(const half8*)(wb + 4 * 512);
            half8 wl2 = *(const half8*)(wb + 5 * 512);
            half8 wh3 = *(const half8*)(wb + 6 * 512);
            half8 wl3 = *(const half8*)(wb + 7 * 512);
            aH[2] = __builtin_amdgcn_mfma_f32_16x16x32_f16(ah, wh2, aH[2], 0, 0, 0);
            aL[2] = __builtin_amdgcn_mfma_f32_16x16x32_f16(ah, wl2, aL[2], 0, 0, 0);
            aL[2] = __builtin_amdgcn_mfma_f32_16x16x32_f16(al, wh2, aL[2], 0, 0, 0);
            aH[3] = __builtin_amdgcn_mfma_f32_16x16x32_f16(ah, wh3, aH[3], 0, 0, 0);
            aL[3] = __builtin_amdgcn_mfma_f32_16x16x32_f16(ah, wl3, aL[3], 0, 0, 0);
            aL[3] = __builtin_amdgcn_mfma_f32_16x16x32_f16(al, wh3, aL[3], 0, 0, 0);
        }
    };

    // one barrier per chunk; NBUF=2: stage(c+1) writes the buf read by
    // compute(c-1), which every wave finished before BAR(c).
    stageX(0, 0);
#pragma unroll 1
    for (int c = 0; c < NCH; ++c) {
        WVM(0);                                  // own stage(c) landed
        BAR();                                   // all waves' stage(c) visible
        if (c + 1 < NCH) stageX((c + 1) & 1, c + 1);
        compute(c & 1, c);
    }

    // ---- reduce 4 kq-partials in LDS (m89-verified C layout) ----
    __syncthreads();                             // before union reuse
    const float inv = 1.f / 4096.f;
#pragma unroll
    for (int e = 0; e < 4; ++e) {
        const int row = (lane >> 4) * 4 + e;     // token 0..15
#pragma unroll
        for (int t = 0; t < 4; ++t)
            sm.red[kq][row][t * 16 + (lane & 15)] = aH[t][e] + aL[t][e] * inv;
    }
    __syncthreads();

    // wave kq writes rows [kq*4, kq*4+4) of this block's partial
    float* pb = partial + (size_t)blockIdx.x * (BM * EE);
#pragma unroll
    for (int rr = 0; rr < 4; ++rr) {
        const int row = kq * 4 + rr;
        float v = (sm.red[0][row][lane] + sm.red[1][row][lane])
                + (sm.red[2][row][lane] + sm.red[3][row][lane]);
        pb[row * EE + lane] = v;
    }
}

// ---- finish: sum 2 K-half partials, softmax/top-2, aux block partials ----
__global__ __launch_bounds__(256) void finish_kernel(
    const float* __restrict__ partial,
    float* __restrict__ gate_out, float* __restrict__ idx_out,
    float* __restrict__ pSum, float* __restrict__ pCnt)
{
    const int tid  = threadIdx.x;
    const int wv   = tid >> 6;       // 0..3
    const int lane = tid & 63;       // = expert id
    __shared__ float auxsm[2][4][64];

    float sumP_acc = 0.f;
    float cnt_acc  = 0.f;
#pragma unroll 1
    for (int tt = 0; tt < 16; ++tt) {
        const size_t t    = (size_t)blockIdx.x * 64 + wv * 16 + tt;
        const size_t tile = t >> 4;
        const int    row  = (int)(t & 15);
        const float* pb = partial + tile * 2 * (BM * EE) + row * EE;
        float v = pb[lane] + pb[BM * EE + lane];   // half0 + half1

        float m = v;
#pragma unroll
        for (int off = 32; off; off >>= 1) m = fmaxf(m, __shfl_xor(m, off, 64));
        float p = expf(v - m);
        float s = p;
#pragma unroll
        for (int off = 32; off; off >>= 1) s += __shfl_xor(s, off, 64);
        float prob = p / s;
        sumP_acc += prob;

        // top-1 (ties -> lowest index, matches lax.top_k)
        float bv = prob; int bi = lane;
#pragma unroll
        for (int off = 32; off; off >>= 1) {
            float ov = __shfl_xor(bv, off, 64);
            int   oi = __shfl_xor(bi, off, 64);
            if (ov > bv || (ov == bv && oi < bi)) { bv = ov; bi = oi; }
        }
        // top-2
        float v2 = (lane == bi) ? -1.f : prob;
        float bv2 = v2; int bi2 = lane;
#pragma unroll
        for (int off = 32; off; off >>= 1) {
            float ov = __shfl_xor(bv2, off, 64);
            int   oi = __shfl_xor(bi2, off, 64);
            if (ov > bv2 || (ov == bv2 && oi < bi2)) { bv2 = ov; bi2 = oi; }
        }

        float denom = bv + bv2;
        float g1 = bv / denom, g2 = bv2 / denom;
        float g = (lane == bi) ? g1 : ((lane == bi2) ? g2 : 0.f);
        gate_out[t * EE + lane] = g;
        if (lane == 0) {
            idx_out[2 * t]     = (float)bi;
            idx_out[2 * t + 1] = (float)bi2;
        }
        cnt_acc += (lane == bi)  ? 1.f : 0.f;
        cnt_acc += (lane == bi2) ? 1.f : 0.f;
    }

    auxsm[0][wv][lane] = sumP_acc;
    auxsm[1][wv][lane] = cnt_acc;
    __syncthreads();
    if (wv == 0) {
        float sp = auxsm[0][0][lane] + auxsm[0][1][lane]
                 + auxsm[0][2][lane] + auxsm[0][3][lane];
        float cc = auxsm[1][0][lane] + auxsm[1][1][lane]
                 + auxsm[1][2][lane] + auxsm[1][3][lane];
        pSum[(size_t)blockIdx.x * 64 + lane] = sp;
        pCnt[(size_t)blockIdx.x * 64 + lane] = cc;
    }
}

// ---- aux final: 1 block over 256 partial rows ----
__global__ __launch_bounds__(256) void aux2_kernel(
    const float* __restrict__ pSum, const float* __restrict__ pCnt,
    float* __restrict__ aux_out, float scale)
{
    const int tid  = threadIdx.x;
    const int wv   = tid >> 6;       // 0..3
    const int lane = tid & 63;       // = expert id
    __shared__ float smem[2][4][64];

    float sp = 0.f, cc = 0.f;
#pragma unroll 1
    for (int b = wv; b < 256; b += 4) {
        sp += pSum[(size_t)b * 64 + lane];
        cc += pCnt[(size_t)b * 64 + lane];
    }
    smem[0][wv][lane] = sp;
    smem[1][wv][lane] = cc;
    __syncthreads();
    if (wv == 0) {
        float SP = smem[0][0][lane] + smem[0][1][lane]
                 + smem[0][2][lane] + smem[0][3][lane];
        float CC = smem[1][0][lane] + smem[1][1][lane]
                 + smem[1][2][lane] + smem[1][3][lane];
        float prod = SP * CC;
#pragma unroll
        for (int off = 32; off; off >>= 1) prod += __shfl_xor(prod, off, 64);
        if (lane == 0) aux_out[0] = prod * scale;
    }
}

extern "C" void kernel_launch(void* const* d_in, const int* in_sizes, int n_in,
                              void* d_out, int out_size, void* d_ws, size_t ws_size,
                              hipStream_t stream) {
    const float* x  = (const float*)d_in[0];
    const float* Wg = (const float*)d_in[1];
    const int T = in_sizes[0] / DD;          // 16384

    float* out      = (float*)d_out;
    float* gate_out = out;                                // T*64
    float* idx_out  = out + (size_t)T * EE;               // T*2 (as float)
    float* aux_out  = idx_out + (size_t)T * 2;            // 1

    const int ntiles = T / BM;                            // 1024
    _Float16* wF   = (_Float16*)d_ws;                     // 512 KB frag-linear
    float* partial = (float*)(wF + (size_t)64 * 8 * 512); // 2048*1024 f32 = 8 MB
    float* pSum    = partial + (size_t)ntiles * 2 * BM * EE;
    float* pCnt    = pSum + 256 * 64;

    wsplit_kernel<<<64, 256, 0, stream>>>(Wg, wF);
    gate_kernel<<<ntiles * 2, 256, 0, stream>>>(x, wF, partial);
    finish_kernel<<<T / 64, 256, 0, stream>>>(partial, gate_out, idx_out,
                                              pSum, pCnt);
    const float scale = (float)EE / ((float)T * (float)T);
    aux2_kernel<<<1, 256, 0, stream>>>(pSum, pCnt, aux_out, scale);
}

// Round 21
// 69.678 us; speedup vs baseline: 1.3008x; 1.3008x over previous
//
#include <hip/hip_runtime.h>

// TopKGate via split-precision f16 MFMA (no fp32 MFMA on CDNA4):
//   x = xh + xl/4096, w = wh + wl/4096 (f16 planes, lo pre-scaled x4096)
//   logits = xh*wh + (xh*wl' + xl'*wh)/4096
// R21: BM=32 with TWO A-fragments per wave -> 24 MFMA per 8 w-loads (w
// L1-return per CU HALVED vs R17; w bytes/block are fixed, tokens/w-read
// is the only lever). R17-proven skeleton: waves = 4 K-quarters, NBUF=3,
// one barrier/chunk, counted WVM(4) (4 DMA/stage). Grid 512 (2 blocks/CU).

typedef __attribute__((ext_vector_type(8))) _Float16 half8;
typedef __attribute__((ext_vector_type(4))) float f32x4;

constexpr int DD  = 2048;
constexpr int EE  = 64;
constexpr int BM  = 32;          // tokens per block (2 A-frags per wave)
constexpr int BK  = 128;         // k per staged chunk (each wave: 32-k quarter)
constexpr int NCH = DD / BK;     // 16 chunks

#define WVM(N) asm volatile("s_waitcnt vmcnt(" #N ")" ::: "memory")
#define BAR()  asm volatile("s_barrier" ::: "memory")

// ---- pre-kernel (R15-proven): Wg[2048][64] -> fragment-linear wF ----
// wF[(kc*8 + t*2 + p)*512 + l*8 + j] = plane_p( Wg[kc*32+(l>>4)*8+j][t*16+(l&15)] )
__global__ __launch_bounds__(256) void wsplit_kernel(
    const float* __restrict__ Wg, _Float16* __restrict__ wF)
{
    __shared__ float xl[32][65];
    const int tid = threadIdx.x;
    const int kc  = blockIdx.x;          // 64 blocks, 32 k's each
    const int k0  = kc * 32;
#pragma unroll
    for (int r = 0; r < 2; ++r) {
        int slot = tid + r * 256;        // float4 slots 0..511
        int row = slot >> 4, c4 = (slot & 15) << 2;
        *(float4*)&xl[row][c4] = *(const float4*)&Wg[(size_t)(k0 + row) * EE + c4];
    }
    __syncthreads();
    const int t = tid >> 6, l = tid & 63;
    const int e  = t * 16 + (l & 15);
    const int kl = (l >> 4) * 8;
    half8 hh, ll;
#pragma unroll
    for (int j = 0; j < 8; ++j) {
        float v = xl[kl + j][e];
        _Float16 h = (_Float16)v;
        hh[j] = h;
        ll[j] = (_Float16)((v - (float)h) * 4096.f);
    }
    const size_t base = (size_t)(kc * 8 + t * 2) * 512 + (size_t)l * 8;
    *(half8*)&wF[base]       = hh;       // hi plane
    *(half8*)&wF[base + 512] = ll;       // lo plane
}

__global__ __launch_bounds__(256, 2) void gate_kernel(
    const float* __restrict__ x, const _Float16* __restrict__ wF,
    float* __restrict__ gate_out, float* __restrict__ idx_out,
    float* __restrict__ pSum, float* __restrict__ pCnt)
{
    __shared__ __align__(16) union {
        float xs[3][BM][BK];                               // 48 KB staging
        struct { float red[4][BM][66]; float auxsm[2][4][64]; } ep; // 35.8 KB
    } sm;

    const int tid  = threadIdx.x;
    const int kq   = tid >> 6;           // wave = K-quarter of chunk (32 k's)
    const int lane = tid & 63;
    const size_t tok0 = (size_t)blockIdx.x * BM;
    const float* xg = x + tok0 * DD;

    // ---- x staging: 4 dwordx4 DMA per thread per chunk, 32B source-XOR ----
    auto stageX = [&](int buf, int c) {
#pragma unroll
        for (int r = 0; r < 4; ++r) {
            int slot = tid + r * 256;            // float4 slot 0..1023
            int row  = slot >> 5;                // 0..31
            int cb   = (slot & 31) << 4;         // dest byte 0..511
            int sb   = cb ^ ((row & 7) << 5);    // source-swizzled byte
            __builtin_amdgcn_global_load_lds(
                xg + (size_t)row * DD + c * BK + (sb >> 2),
                &sm.xs[buf][row][cb >> 2], 16, 0, 0);
        }
    };

    f32x4 aH[2][4], aL[2][4];
#pragma unroll
    for (int f = 0; f < 2; ++f)
#pragma unroll
        for (int t = 0; t < 4; ++t) {
            aH[f][t] = (f32x4){0.f, 0.f, 0.f, 0.f};
            aL[f][t] = (f32x4){0.f, 0.f, 0.f, 0.f};
        }

    const int rrow = lane & 15;          // token row (frag 0); frag 1 = +16
    const int rb   = (kq * 128 + ((lane >> 4) * 32)) ^ ((rrow & 7) << 5);

    auto compute = [&](int buf, int c) {
        // w fragments for this wave's 32-k slice (kc = c*4 + kq), all 4 tiles
        const _Float16* wb = wF + (size_t)(c * 4 + kq) * 4096 + (size_t)lane * 8;
        half8 wh[4], wl[4];
#pragma unroll
        for (int t = 0; t < 4; ++t) {
            wh[t] = *(const half8*)(wb + (t * 2) * 512);
            wl[t] = *(const half8*)(wb + (t * 2 + 1) * 512);
        }
#pragma unroll
        for (int f = 0; f < 2; ++f) {
            const float* p = (const float*)
                ((const char*)&sm.xs[buf][rrow + f * 16][0] + rb);
            float4 xa = *(const float4*)p;
            float4 xb = *(const float4*)(p + 4);
            half8 ah, al;
            {
                float v;
                v = xa.x; { _Float16 h=(_Float16)v; ah[0]=h; al[0]=(_Float16)((v-(float)h)*4096.f); }
                v = xa.y; { _Float16 h=(_Float16)v; ah[1]=h; al[1]=(_Float16)((v-(float)h)*4096.f); }
                v = xa.z; { _Float16 h=(_Float16)v; ah[2]=h; al[2]=(_Float16)((v-(float)h)*4096.f); }
                v = xa.w; { _Float16 h=(_Float16)v; ah[3]=h; al[3]=(_Float16)((v-(float)h)*4096.f); }
                v = xb.x; { _Float16 h=(_Float16)v; ah[4]=h; al[4]=(_Float16)((v-(float)h)*4096.f); }
                v = xb.y; { _Float16 h=(_Float16)v; ah[5]=h; al[5]=(_Float16)((v-(float)h)*4096.f); }
                v = xb.z; { _Float16 h=(_Float16)v; ah[6]=h; al[6]=(_Float16)((v-(float)h)*4096.f); }
                v = xb.w; { _Float16 h=(_Float16)v; ah[7]=h; al[7]=(_Float16)((v-(float)h)*4096.f); }
            }
#pragma unroll
            for (int t = 0; t < 4; ++t) {
                aH[f][t] = __builtin_amdgcn_mfma_f32_16x16x32_f16(ah, wh[t], aH[f][t], 0, 0, 0);
                aL[f][t] = __builtin_amdgcn_mfma_f32_16x16x32_f16(ah, wl[t], aL[f][t], 0, 0, 0);
                aL[f][t] = __builtin_amdgcn_mfma_f32_16x16x32_f16(al, wh[t], aL[f][t], 0, 0, 0);
            }
        }
    };

    // prologue: 2 stages in flight (4 DMA each)
    stageX(0, 0);
    stageX(1, 1);

    // one barrier per chunk (NBUF=3: stage(c+2) writes the buf consumed by
    // compute(c-1), which every wave passed before BAR(c)). Counted waits.
#pragma unroll 1
    for (int c = 0; c < NCH; ++c) {
        if (c < NCH - 1) { WVM(4); } else { WVM(0); }  // own stage(c) landed
        BAR();                                   // all waves' stage(c) visible
        compute(c % 3, c);
        if (c + 2 < NCH) stageX((c + 2) % 3, c + 2);
    }

    // ---- K-partials -> LDS (m89-verified C layout), combine planes ----
    __syncthreads();
    const float inv = 1.f / 4096.f;
#pragma unroll
    for (int f = 0; f < 2; ++f)
#pragma unroll
        for (int e = 0; e < 4; ++e) {
            const int row = f * 16 + (lane >> 4) * 4 + e;  // token 0..31
#pragma unroll
            for (int t = 0; t < 4; ++t)
                sm.ep.red[kq][row][t * 16 + (lane & 15)] =
                    aH[f][t][e] + aL[f][t][e] * inv;
        }
    __syncthreads();

    // ---- epilogue: wave kq -> tokens [kq*8, kq*8+8); lane = expert ----
    float sumP_acc = 0.f;
    float cnt_acc  = 0.f;
#pragma unroll 1
    for (int tt = 0; tt < 8; ++tt) {
        const int tl = kq * 8 + tt;
        const size_t t = tok0 + tl;
        float v = (sm.ep.red[0][tl][lane] + sm.ep.red[1][tl][lane])
                + (sm.ep.red[2][tl][lane] + sm.ep.red[3][tl][lane]);

        float m = v;
#pragma unroll
        for (int off = 32; off; off >>= 1) m = fmaxf(m, __shfl_xor(m, off, 64));
        float p = expf(v - m);
        float s = p;
#pragma unroll
        for (int off = 32; off; off >>= 1) s += __shfl_xor(s, off, 64);
        float prob = p / s;
        sumP_acc += prob;

        // top-1 (ties -> lowest index, matches lax.top_k)
        float bv = prob; int bi = lane;
#pragma unroll
        for (int off = 32; off; off >>= 1) {
            float ov = __shfl_xor(bv, off, 64);
            int   oi = __shfl_xor(bi, off, 64);
            if (ov > bv || (ov == bv && oi < bi)) { bv = ov; bi = oi; }
        }
        // top-2
        float v2 = (lane == bi) ? -1.f : prob;
        float bv2 = v2; int bi2 = lane;
#pragma unroll
        for (int off = 32; off; off >>= 1) {
            float ov = __shfl_xor(bv2, off, 64);
            int   oi = __shfl_xor(bi2, off, 64);
            if (ov > bv2 || (ov == bv2 && oi < bi2)) { bv2 = ov; bi2 = oi; }
        }

        float denom = bv + bv2;
        float g1 = bv / denom, g2 = bv2 / denom;
        float g = (lane == bi) ? g1 : ((lane == bi2) ? g2 : 0.f);
        gate_out[t * EE + lane] = g;
        if (lane == 0) {
            idx_out[2 * t]     = (float)bi;
            idx_out[2 * t + 1] = (float)bi2;
        }
        cnt_acc += (lane == bi)  ? 1.f : 0.f;
        cnt_acc += (lane == bi2) ? 1.f : 0.f;
    }

    // ---- per-block aux partials (deterministic) ----
    sm.ep.auxsm[0][kq][lane] = sumP_acc;
    sm.ep.auxsm[1][kq][lane] = cnt_acc;
    __syncthreads();
    if (kq == 0) {
        float sp = 0.f, c2 = 0.f;
#pragma unroll
        for (int w = 0; w < 4; ++w) {
            sp += sm.ep.auxsm[0][w][lane];
            c2 += sm.ep.auxsm[1][w][lane];
        }
        pSum[(size_t)blockIdx.x * 64 + lane] = sp;
        pCnt[(size_t)blockIdx.x * 64 + lane] = c2;
    }
}

// ---- aux stage 1: 64 blocks, each reduces 8 source rows (all experts) ----
__global__ __launch_bounds__(256) void aux1_kernel(
    const float* __restrict__ pSum, const float* __restrict__ pCnt,
    float* __restrict__ p2Sum, float* __restrict__ p2Cnt)
{
    const int tid  = threadIdx.x;
    const int wv   = tid >> 6;       // 0..3
    const int lane = tid & 63;       // = expert id
    __shared__ float smem[2][4][64];

    const int r0 = blockIdx.x * 8 + wv * 2;
    float sp = 0.f, cc = 0.f;
#pragma unroll
    for (int u = 0; u < 2; ++u) {
        sp += pSum[(size_t)(r0 + u) * 64 + lane];
        cc += pCnt[(size_t)(r0 + u) * 64 + lane];
    }
    smem[0][wv][lane] = sp;
    smem[1][wv][lane] = cc;
    __syncthreads();
    if (wv == 0) {
        float SP = smem[0][0][lane] + smem[0][1][lane]
                 + smem[0][2][lane] + smem[0][3][lane];
        float CC = smem[1][0][lane] + smem[1][1][lane]
                 + smem[1][2][lane] + smem[1][3][lane];
        p2Sum[(size_t)blockIdx.x * 64 + lane] = SP;
        p2Cnt[(size_t)blockIdx.x * 64 + lane] = CC;
    }
}

// ---- aux stage 2: 1 block over 64 partials ----
__global__ __launch_bounds__(256) void aux2_kernel(
    const float* __restrict__ p2Sum, const float* __restrict__ p2Cnt,
    float* __restrict__ aux_out, float scale)
{
    const int tid  = threadIdx.x;
    const int wv   = tid >> 6;       // 0..3
    const int lane = tid & 63;       // = expert id
    __shared__ float smem[2][4][64];

    float sp = 0.f, cc = 0.f;
#pragma unroll 1
    for (int b = wv * 16; b < wv * 16 + 16; ++b) {
        sp += p2Sum[(size_t)b * 64 + lane];
        cc += p2Cnt[(size_t)b * 64 + lane];
    }
    smem[0][wv][lane] = sp;
    smem[1][wv][lane] = cc;
    __syncthreads();
    if (wv == 0) {
        float SP = smem[0][0][lane] + smem[0][1][lane]
                 + smem[0][2][lane] + smem[0][3][lane];
        float CC = smem[1][0][lane] + smem[1][1][lane]
                 + smem[1][2][lane] + smem[1][3][lane];
        float prod = SP * CC;
#pragma unroll
        for (int off = 32; off; off >>= 1) prod += __shfl_xor(prod, off, 64);
        if (lane == 0) aux_out[0] = prod * scale;
    }
}

extern "C" void kernel_launch(void* const* d_in, const int* in_sizes, int n_in,
                              void* d_out, int out_size, void* d_ws, size_t ws_size,
                              hipStream_t stream) {
    const float* x  = (const float*)d_in[0];
    const float* Wg = (const float*)d_in[1];
    const int T = in_sizes[0] / DD;          // 16384

    float* out      = (float*)d_out;
    float* gate_out = out;                                // T*64
    float* idx_out  = out + (size_t)T * EE;               // T*2 (as float)
    float* aux_out  = idx_out + (size_t)T * 2;            // 1

    const int nblocks = T / BM;                           // 512
    _Float16* wF = (_Float16*)d_ws;                       // 512 KB frag-linear
    float* pSum  = (float*)(wF + (size_t)64 * 8 * 512);   // 512*64
    float* pCnt  = pSum + (size_t)nblocks * 64;           // 512*64
    float* p2Sum = pCnt + (size_t)nblocks * 64;           // 64*64
    float* p2Cnt = p2Sum + 64 * 64;                       // 64*64

    wsplit_kernel<<<64, 256, 0, stream>>>(Wg, wF);
    gate_kernel<<<nblocks, 256, 0, stream>>>(x, wF, gate_out, idx_out, pSum, pCnt);

    const float scale = (float)EE / ((float)T * (float)T);
    aux1_kernel<<<64, 256, 0, stream>>>(pSum, pCnt, p2Sum, p2Cnt);
    aux2_kernel<<<1, 256, 0, stream>>>(p2Sum, p2Cnt, aux_out, scale);
}